// Round 1
// baseline (1405.388 us; speedup 1.0000x reference)
//
#include <hip/hip_runtime.h>
#include <hip/hip_bf16.h>

#define B_ 16
#define S_ 512
#define E_ 256
#define H_ 4
#define D_ 64
#define L_ 2
#define MAXPOS 10

// ---------------- gather: x = input_embed[item_inputs], qb = query_embed[item_ids]
__global__ __launch_bounds__(256) void gather_kernel(
    const int* __restrict__ item_inputs, const int* __restrict__ item_ids,
    const float* __restrict__ input_embed, const float* __restrict__ query_embed,
    float* __restrict__ x, float* __restrict__ qb)
{
    int row = blockIdx.x;
    int e = threadIdx.x;
    int ii = item_inputs[row];
    int qi = item_ids[row];
    x[(size_t)row * E_ + e]  = input_embed[(size_t)ii * E_ + e];
    qb[(size_t)row * E_ + e] = query_embed[(size_t)qi * E_ + e];
}

// ---------------- tiled f32 GEMM: C = A[M,K] @ W[K,N] + bias
// MODE 0: C = result;  MODE 1: C += relu(result)
#define TM 64
#define TN 64
#define TK 32

template<int MODE>
__global__ __launch_bounds__(256) void gemm_kernel(
    const float* __restrict__ A, const float* __restrict__ W,
    const float* __restrict__ bias, float* __restrict__ C,
    int M, int N, int K)
{
    __shared__ float At[TK][68];   // A tile transposed [k][m], pad to 68 for b128-aligned reads
    __shared__ float Ws[TK][TN];
    const int bm = blockIdx.x, bn = blockIdx.y;
    const int tid = threadIdx.x;
    const int tx = tid & 15, ty = tid >> 4;
    const int rowA = bm * TM;
    const int colW = bn * TN;
    float acc[4][4] = {{0.0f}};

    for (int k0 = 0; k0 < K; k0 += TK) {
        // load A tile 64x32 (transposed into LDS)
        {
            int r = tid >> 3, kq = tid & 7;
            #pragma unroll
            for (int rr = 0; rr < 2; ++rr) {
                const float4 v = *reinterpret_cast<const float4*>(
                    &A[(size_t)(rowA + r + rr * 32) * K + k0 + kq * 4]);
                At[kq * 4 + 0][r + rr * 32] = v.x;
                At[kq * 4 + 1][r + rr * 32] = v.y;
                At[kq * 4 + 2][r + rr * 32] = v.z;
                At[kq * 4 + 3][r + rr * 32] = v.w;
            }
        }
        // load W tile 32x64
        {
            int kk = tid >> 4, cq = tid & 15;
            #pragma unroll
            for (int rr = 0; rr < 2; ++rr) {
                const float4 v = *reinterpret_cast<const float4*>(
                    &W[(size_t)(k0 + kk + rr * 16) * N + colW + cq * 4]);
                *reinterpret_cast<float4*>(&Ws[kk + rr * 16][cq * 4]) = v;
            }
        }
        __syncthreads();
        #pragma unroll
        for (int kk = 0; kk < TK; ++kk) {
            const float4 a = *reinterpret_cast<const float4*>(&At[kk][ty * 4]);
            const float4 w = *reinterpret_cast<const float4*>(&Ws[kk][tx * 4]);
            const float av[4] = {a.x, a.y, a.z, a.w};
            const float wv[4] = {w.x, w.y, w.z, w.w};
            #pragma unroll
            for (int i = 0; i < 4; ++i)
                #pragma unroll
                for (int j = 0; j < 4; ++j)
                    acc[i][j] += av[i] * wv[j];
        }
        __syncthreads();
    }

    const int r0 = rowA + ty * 4, c0 = colW + tx * 4;
    #pragma unroll
    for (int i = 0; i < 4; ++i) {
        #pragma unroll
        for (int j = 0; j < 4; ++j) {
            float v = acc[i][j] + bias[c0 + j];
            size_t idx = (size_t)(r0 + i) * N + c0 + j;
            if (MODE == 0) C[idx] = v;
            else           C[idx] += fmaxf(v, 0.0f);
        }
    }
}

// ---------------- attention: one block per (b,h,i) row
__global__ __launch_bounds__(256) void attn_kernel(
    const float* __restrict__ Q, const float* __restrict__ K,
    const float* __restrict__ V, const float* __restrict__ pos_key,
    const float* __restrict__ pos_value, float* __restrict__ merged)
{
    __shared__ float q_sh[D_];
    __shared__ float qpk[MAXPOS];
    __shared__ float sc[S_];
    __shared__ float red[256];
    __shared__ float opart[4][D_];

    const int bid = blockIdx.x;
    const int i = bid & (S_ - 1);
    const int bh = bid >> 9;          // S_ = 512
    const int h = bh & (H_ - 1);
    const int b = bh >> 2;            // H_ = 4
    const int tid = threadIdx.x;

    const size_t qoff = ((size_t)(b * S_ + i)) * E_ + h * D_;
    if (tid < D_) q_sh[tid] = Q[qoff + tid];
    __syncthreads();
    if (tid < MAXPOS) {
        float s = 0.0f;
        #pragma unroll
        for (int d = 0; d < D_; ++d) s += q_sh[d] * pos_key[tid * D_ + d];
        qpk[tid] = s;
    }
    __syncthreads();

    const int n = i + 1;              // attend to j <= i
    const float scale = 0.125f;       // 1/sqrt(64)

    float lmax = -1e30f;
    for (int j = tid; j < n; j += 256) {
        const float* kr = &K[((size_t)(b * S_ + j)) * E_ + h * D_];
        float s = 0.0f;
        #pragma unroll
        for (int d4 = 0; d4 < D_ / 4; ++d4) {
            const float4 kv = reinterpret_cast<const float4*>(kr)[d4];
            s += q_sh[d4 * 4 + 0] * kv.x + q_sh[d4 * 4 + 1] * kv.y
               + q_sh[d4 * 4 + 2] * kv.z + q_sh[d4 * 4 + 3] * kv.w;
        }
        s = (s + qpk[min(i - j, MAXPOS - 1)]) * scale;
        sc[j] = s;
        lmax = fmaxf(lmax, s);
    }
    red[tid] = lmax; __syncthreads();
    for (int st = 128; st > 0; st >>= 1) {
        if (tid < st) red[tid] = fmaxf(red[tid], red[tid + st]);
        __syncthreads();
    }
    const float m = red[0];
    __syncthreads();

    float lsum = 0.0f;
    for (int j = tid; j < n; j += 256) {
        const float e = __expf(sc[j] - m);
        sc[j] = e;
        lsum += e;
    }
    red[tid] = lsum; __syncthreads();
    for (int st = 128; st > 0; st >>= 1) {
        if (tid < st) red[tid] += red[tid + st];
        __syncthreads();
    }
    const float inv = 1.0f / red[0];
    __syncthreads();
    for (int j = tid; j < n; j += 256) sc[j] *= inv;
    __syncthreads();

    // out_d = sum_j p_j * V[j,d]; 4 j-partitions x 64 dims
    const int d = tid & (D_ - 1);
    const int g = tid >> 6;
    float acc = 0.0f;
    for (int j = g; j < n; j += 4)
        acc += sc[j] * V[((size_t)(b * S_ + j)) * E_ + h * D_ + d];
    opart[g][d] = acc;
    __syncthreads();

    if (tid < D_) {
        float o = opart[0][tid] + opart[1][tid] + opart[2][tid] + opart[3][tid];
        // pos_value part via 10 rel-distance buckets; bucket 9 = 1 - sum(others)
        float rest = 1.0f;
        #pragma unroll
        for (int r = 0; r < MAXPOS - 1; ++r) {
            if (i - r >= 0) {
                const float p = sc[i - r];
                rest -= p;
                o += p * pos_value[r * D_ + tid];
            }
        }
        if (i >= MAXPOS - 1) o += rest * pos_value[(MAXPOS - 1) * D_ + tid];
        merged[qoff + tid] = o;
    }
}

// ---------------- final: y[row] = dot(out[row,:], out_w) + out_b
__global__ __launch_bounds__(256) void final_kernel(
    const float* __restrict__ x, const float* __restrict__ w,
    const float* __restrict__ b, float* __restrict__ y)
{
    __shared__ float red[256];
    const int row = blockIdx.x, tid = threadIdx.x;
    red[tid] = x[(size_t)row * E_ + tid] * w[tid];
    __syncthreads();
    for (int st = 128; st > 0; st >>= 1) {
        if (tid < st) red[tid] += red[tid + st];
        __syncthreads();
    }
    if (tid == 0) y[row] = red[0] + b[0];
}

extern "C" void kernel_launch(void* const* d_in, const int* in_sizes, int n_in,
                              void* d_out, int out_size, void* d_ws, size_t ws_size,
                              hipStream_t stream) {
    const int*   item_inputs = (const int*)d_in[0];
    const int*   item_ids    = (const int*)d_in[1];
    const float* input_embed = (const float*)d_in[2];
    const float* query_embed = (const float*)d_in[3];
    const float* pos_key     = (const float*)d_in[4];
    const float* pos_value   = (const float*)d_in[5];
    const float* Wq = (const float*)d_in[6];
    const float* bq = (const float*)d_in[7];
    const float* Wk = (const float*)d_in[8];
    const float* bk = (const float*)d_in[9];
    const float* Wv = (const float*)d_in[10];
    const float* bv = (const float*)d_in[11];
    const float* Wo = (const float*)d_in[12];
    const float* bo = (const float*)d_in[13];
    const float* out_w = (const float*)d_in[14];
    const float* out_b = (const float*)d_in[15];
    float* y = (float*)d_out;

    const int M = B_ * S_;                  // 8192 rows
    const size_t SZ = (size_t)M * E_;       // 2,097,152 floats per buffer
    float* ws  = (float*)d_ws;
    float* out = ws;            // running hidden state [M,E]
    float* qb  = ws + 1 * SZ;   // query base [M,E]
    float* Qb  = ws + 2 * SZ;
    float* Kb  = ws + 3 * SZ;
    float* Vb  = ws + 4 * SZ;
    float* mg  = ws + 5 * SZ;   // merged attention output

    gather_kernel<<<M, 256, 0, stream>>>(item_inputs, item_ids, input_embed,
                                         query_embed, out, qb);

    dim3 ggrid(M / TM, E_ / TN);
    for (int l = 0; l < L_; ++l) {
        const float* wq = Wq + (size_t)l * E_ * E_;
        const float* wk = Wk + (size_t)l * E_ * E_;
        const float* wv = Wv + (size_t)l * E_ * E_;
        const float* wo = Wo + (size_t)l * E_ * E_;
        gemm_kernel<0><<<ggrid, 256, 0, stream>>>(qb,  wq, bq + l * E_, Qb, M, E_, E_);
        gemm_kernel<0><<<ggrid, 256, 0, stream>>>(out, wk, bk + l * E_, Kb, M, E_, E_);
        gemm_kernel<0><<<ggrid, 256, 0, stream>>>(out, wv, bv + l * E_, Vb, M, E_, E_);
        attn_kernel<<<B_ * H_ * S_, 256, 0, stream>>>(Qb, Kb, Vb, pos_key, pos_value, mg);
        gemm_kernel<1><<<ggrid, 256, 0, stream>>>(mg, wo, bo + l * E_, out, M, E_, E_);
    }

    final_kernel<<<M, 256, 0, stream>>>(out, out_w, out_b, y);
}

// Round 2
// 225.898 us; speedup vs baseline: 6.2213x; 6.2213x over previous
//
#include <hip/hip_runtime.h>
#include <hip/hip_bf16.h>

#define B_ 16
#define S_ 512
#define E_ 256
#define H_ 4
#define D_ 64
#define L_ 2
#define MAXPOS 10

typedef __attribute__((ext_vector_type(8))) short bf16x8;
typedef __attribute__((ext_vector_type(4))) float f32x4;

static __device__ __forceinline__ short f2bf(float f) {
    __hip_bfloat16 h = __float2bfloat16(f);
    return __builtin_bit_cast(short, h);
}
static __device__ __forceinline__ float bf2f(short s) {
    unsigned int u = ((unsigned int)(unsigned short)s) << 16;
    return __builtin_bit_cast(float, u);
}

// ---------------- gather: x = input_embed[item_inputs], qb = query_embed[item_ids]
__global__ __launch_bounds__(256) void gather_kernel(
    const int* __restrict__ item_inputs, const int* __restrict__ item_ids,
    const float* __restrict__ input_embed, const float* __restrict__ query_embed,
    float* __restrict__ x, float* __restrict__ qb)
{
    int row = blockIdx.x;
    int e = threadIdx.x;
    int ii = item_inputs[row];
    int qi = item_ids[row];
    x[(size_t)row * E_ + e]  = input_embed[(size_t)ii * E_ + e];
    qb[(size_t)row * E_ + e] = query_embed[(size_t)qi * E_ + e];
}

// ---------------- tiled f32 GEMM: C = A[M,K] @ W[K,N] + bias
// MODE 0: C = result;  MODE 1: C += relu(result)
#define TM 64
#define TN 64
#define TK 32

template<int MODE>
__global__ __launch_bounds__(256) void gemm_kernel(
    const float* __restrict__ A, const float* __restrict__ W,
    const float* __restrict__ bias, float* __restrict__ C,
    int M, int N, int K)
{
    __shared__ float At[TK][68];
    __shared__ float Ws[TK][TN];
    const int bm = blockIdx.x, bn = blockIdx.y;
    const int tid = threadIdx.x;
    const int tx = tid & 15, ty = tid >> 4;
    const int rowA = bm * TM;
    const int colW = bn * TN;
    float acc[4][4] = {{0.0f}};

    for (int k0 = 0; k0 < K; k0 += TK) {
        {
            int r = tid >> 3, kq = tid & 7;
            #pragma unroll
            for (int rr = 0; rr < 2; ++rr) {
                const float4 v = *reinterpret_cast<const float4*>(
                    &A[(size_t)(rowA + r + rr * 32) * K + k0 + kq * 4]);
                At[kq * 4 + 0][r + rr * 32] = v.x;
                At[kq * 4 + 1][r + rr * 32] = v.y;
                At[kq * 4 + 2][r + rr * 32] = v.z;
                At[kq * 4 + 3][r + rr * 32] = v.w;
            }
        }
        {
            int kk = tid >> 4, cq = tid & 15;
            #pragma unroll
            for (int rr = 0; rr < 2; ++rr) {
                const float4 v = *reinterpret_cast<const float4*>(
                    &W[(size_t)(k0 + kk + rr * 16) * N + colW + cq * 4]);
                *reinterpret_cast<float4*>(&Ws[kk + rr * 16][cq * 4]) = v;
            }
        }
        __syncthreads();
        #pragma unroll
        for (int kk = 0; kk < TK; ++kk) {
            const float4 a = *reinterpret_cast<const float4*>(&At[kk][ty * 4]);
            const float4 w = *reinterpret_cast<const float4*>(&Ws[kk][tx * 4]);
            const float av[4] = {a.x, a.y, a.z, a.w};
            const float wv[4] = {w.x, w.y, w.z, w.w};
            #pragma unroll
            for (int i = 0; i < 4; ++i)
                #pragma unroll
                for (int j = 0; j < 4; ++j)
                    acc[i][j] += av[i] * wv[j];
        }
        __syncthreads();
    }

    const int r0 = rowA + ty * 4, c0 = colW + tx * 4;
    #pragma unroll
    for (int i = 0; i < 4; ++i) {
        #pragma unroll
        for (int j = 0; j < 4; ++j) {
            float v = acc[i][j] + bias[c0 + j];
            size_t idx = (size_t)(r0 + i) * N + c0 + j;
            if (MODE == 0) C[idx] = v;
            else           C[idx] += fmaxf(v, 0.0f);
        }
    }
}

// ---------------- flash-style MFMA attention
// Block: 256 threads = 4 waves. Grid: B*H*(S/64) = 512.
// Block handles 64 q-rows of one (b,h); wave w owns rows [16w,16w+16).
// Scores are tiny (|s|<~1e-2) -> exp() without max-subtraction is safe; single
// pass, no online rescale. pos_value via 10 buckets: 0..8 are the (unique)
// near-diagonal p values, bucket 9 = lsum - sum(others).
__global__ __launch_bounds__(256) void attn_mfma_kernel(
    const float* __restrict__ Q, const float* __restrict__ K,
    const float* __restrict__ V, const float* __restrict__ pos_key,
    const float* __restrict__ pos_value, float* __restrict__ merged)
{
    __shared__ short Qs[64 * 72];     // [row][d], bf16, +8 pad
    __shared__ short Ks[64 * 72];     // [j][d]
    __shared__ short Vts[64 * 72];    // [d][j]  (V transposed)
    __shared__ short Pl[4 * 16 * 72]; // per-wave P tile [16 rows][64 j]
    __shared__ float pk_sh[MAXPOS * 64];
    __shared__ float pv_sh[MAXPOS * 64];
    __shared__ float qpk_sh[64 * MAXPOS]; // [row][rel]
    __shared__ float pdiag[64 * 9];       // unnormalized p at rel 0..8

    const int bid = blockIdx.x;
    const int it = bid & 7;
    const int h  = (bid >> 3) & 3;
    const int b  = bid >> 5;
    const int tid = threadIdx.x;
    const int lane = tid & 63;
    const int w = tid >> 6;
    const int l15 = lane & 15;
    const int l4  = lane >> 4;
    const int rloc  = l4 * 4;          // row-in-wave base (D-frag rows)
    const int rbase = w * 16 + rloc;   // row within the 64-row tile

    const size_t headoff = ((size_t)b * S_) * E_ + h * D_;

    // ---- stage pos tables, Q tile; zero pdiag
    for (int idx = tid; idx < MAXPOS * 64; idx += 256) {
        pk_sh[idx] = pos_key[idx];
        pv_sh[idx] = pos_value[idx];
    }
    for (int idx = tid; idx < 64 * 9; idx += 256) pdiag[idx] = 0.0f;
    {
        const int row = tid >> 2, dq = (tid & 3) * 16;
        const float* src = &Q[headoff + (size_t)(it * 64 + row) * E_ + dq];
        #pragma unroll
        for (int q = 0; q < 4; ++q) {
            const float4 v = reinterpret_cast<const float4*>(src)[q];
            short4 s4 = { f2bf(v.x), f2bf(v.y), f2bf(v.z), f2bf(v.w) };
            *reinterpret_cast<short4*>(&Qs[row * 72 + dq + q * 4]) = s4;
        }
    }
    __syncthreads();

    // ---- qpk[row][r] = q_row . pos_key[r]
    for (int task = tid; task < MAXPOS * 64; task += 256) {
        const int r = task >> 6, row = task & 63;
        float s = 0.0f;
        #pragma unroll
        for (int d = 0; d < 64; ++d) s += bf2f(Qs[row * 72 + d]) * pk_sh[r * 64 + d];
        qpk_sh[row * MAXPOS + r] = s;
    }

    // hoist Q A-frags (loop-invariant)
    bf16x8 aq[2];
    #pragma unroll
    for (int ks = 0; ks < 2; ++ks)
        aq[ks] = *reinterpret_cast<const bf16x8*>(
            &Qs[(w * 16 + l15) * 72 + ks * 32 + 8 * l4]);

    __syncthreads();   // qpk_sh ready

    float q9[4];
    #pragma unroll
    for (int r = 0; r < 4; ++r) q9[r] = qpk_sh[(rbase + r) * MAXPOS + 9];

    f32x4 accv[4];
    #pragma unroll
    for (int nf = 0; nf < 4; ++nf) accv[nf] = (f32x4){0.f, 0.f, 0.f, 0.f};
    float ls[4] = {0.f, 0.f, 0.f, 0.f};

    for (int jt = 0; jt <= it; ++jt) {
        // ---- stage K (row-major) and V (transposed) as bf16
        {
            const int row = tid >> 2, dq = (tid & 3) * 16;
            const float* ksrc = &K[headoff + (size_t)(jt * 64 + row) * E_ + dq];
            const float* vsrc = &V[headoff + (size_t)(jt * 64 + row) * E_ + dq];
            #pragma unroll
            for (int q = 0; q < 4; ++q) {
                const float4 kv = reinterpret_cast<const float4*>(ksrc)[q];
                short4 s4 = { f2bf(kv.x), f2bf(kv.y), f2bf(kv.z), f2bf(kv.w) };
                *reinterpret_cast<short4*>(&Ks[row * 72 + dq + q * 4]) = s4;
                const float4 vv = reinterpret_cast<const float4*>(vsrc)[q];
                const int d0 = dq + q * 4;
                Vts[(d0 + 0) * 72 + row] = f2bf(vv.x);
                Vts[(d0 + 1) * 72 + row] = f2bf(vv.y);
                Vts[(d0 + 2) * 72 + row] = f2bf(vv.z);
                Vts[(d0 + 3) * 72 + row] = f2bf(vv.w);
            }
        }
        __syncthreads();

        // ---- scores + exp -> Pl
        const bool near = (jt >= it - 1);
        #pragma unroll
        for (int nf = 0; nf < 4; ++nf) {
            f32x4 c = (f32x4){0.f, 0.f, 0.f, 0.f};
            const bf16x8 bk0 = *reinterpret_cast<const bf16x8*>(
                &Ks[(nf * 16 + l15) * 72 + 0 + 8 * l4]);
            const bf16x8 bk1 = *reinterpret_cast<const bf16x8*>(
                &Ks[(nf * 16 + l15) * 72 + 32 + 8 * l4]);
            c = __builtin_amdgcn_mfma_f32_16x16x32_bf16(aq[0], bk0, c, 0, 0, 0);
            c = __builtin_amdgcn_mfma_f32_16x16x32_bf16(aq[1], bk1, c, 0, 0, 0);
            const int j = jt * 64 + nf * 16 + l15;
            #pragma unroll
            for (int r = 0; r < 4; ++r) {
                float p;
                if (near) {
                    const int i = it * 64 + rbase + r;
                    const int rel = i - j;
                    if (rel < 0) p = 0.0f;
                    else {
                        const int rc = rel < 9 ? rel : 9;
                        p = __expf((c[r] + qpk_sh[(rbase + r) * MAXPOS + rc]) * 0.125f);
                        if (rel < 9) pdiag[(rbase + r) * 9 + rel] = p;
                    }
                } else {
                    p = __expf((c[r] + q9[r]) * 0.125f);
                }
                ls[r] += p;
                Pl[w * 1152 + (rloc + r) * 72 + nf * 16 + l15] = f2bf(p);
            }
        }
        __syncthreads();

        // ---- PV accumulate
        #pragma unroll
        for (int ks = 0; ks < 2; ++ks) {
            const bf16x8 pa = *reinterpret_cast<const bf16x8*>(
                &Pl[w * 1152 + l15 * 72 + ks * 32 + 8 * l4]);
            #pragma unroll
            for (int nf = 0; nf < 4; ++nf) {
                const bf16x8 bv = *reinterpret_cast<const bf16x8*>(
                    &Vts[(nf * 16 + l15) * 72 + ks * 32 + 8 * l4]);
                accv[nf] = __builtin_amdgcn_mfma_f32_16x16x32_bf16(pa, bv, accv[nf], 0, 0, 0);
            }
        }
        __syncthreads();
    }

    // ---- row sums: reduce ls across the 16 lanes sharing rows
    #pragma unroll
    for (int m = 1; m < 16; m <<= 1) {
        #pragma unroll
        for (int r = 0; r < 4; ++r) ls[r] += __shfl_xor(ls[r], m, 64);
    }

    // ---- epilogue: normalize + pos_value buckets
    #pragma unroll
    for (int r = 0; r < 4; ++r) {
        const int rowl = rbase + r;
        const float inv = 1.0f / ls[r];
        #pragma unroll
        for (int nf = 0; nf < 4; ++nf) {
            const int col = nf * 16 + l15;
            const float pv9 = pv_sh[9 * 64 + col];
            float extra = ls[r] * pv9;
            #pragma unroll
            for (int rr = 0; rr < 9; ++rr)
                extra += pdiag[rowl * 9 + rr] * (pv_sh[rr * 64 + col] - pv9);
            merged[headoff + (size_t)(it * 64 + rowl) * E_ + col] =
                (accv[nf][r] + extra) * inv;
        }
    }
}

// ---------------- final: y[row] = dot(out[row,:], out_w) + out_b
__global__ __launch_bounds__(256) void final_kernel(
    const float* __restrict__ x, const float* __restrict__ w,
    const float* __restrict__ b, float* __restrict__ y)
{
    __shared__ float red[256];
    const int row = blockIdx.x, tid = threadIdx.x;
    red[tid] = x[(size_t)row * E_ + tid] * w[tid];
    __syncthreads();
    for (int st = 128; st > 0; st >>= 1) {
        if (tid < st) red[tid] += red[tid + st];
        __syncthreads();
    }
    if (tid == 0) y[row] = red[0] + b[0];
}

extern "C" void kernel_launch(void* const* d_in, const int* in_sizes, int n_in,
                              void* d_out, int out_size, void* d_ws, size_t ws_size,
                              hipStream_t stream) {
    const int*   item_inputs = (const int*)d_in[0];
    const int*   item_ids    = (const int*)d_in[1];
    const float* input_embed = (const float*)d_in[2];
    const float* query_embed = (const float*)d_in[3];
    const float* pos_key     = (const float*)d_in[4];
    const float* pos_value   = (const float*)d_in[5];
    const float* Wq = (const float*)d_in[6];
    const float* bq = (const float*)d_in[7];
    const float* Wk = (const float*)d_in[8];
    const float* bk = (const float*)d_in[9];
    const float* Wv = (const float*)d_in[10];
    const float* bv = (const float*)d_in[11];
    const float* Wo = (const float*)d_in[12];
    const float* bo = (const float*)d_in[13];
    const float* out_w = (const float*)d_in[14];
    const float* out_b = (const float*)d_in[15];
    float* y = (float*)d_out;

    const int M = B_ * S_;
    const size_t SZ = (size_t)M * E_;
    float* ws  = (float*)d_ws;
    float* out = ws;
    float* qb  = ws + 1 * SZ;
    float* Qb  = ws + 2 * SZ;
    float* Kb  = ws + 3 * SZ;
    float* Vb  = ws + 4 * SZ;
    float* mg  = ws + 5 * SZ;

    gather_kernel<<<M, 256, 0, stream>>>(item_inputs, item_ids, input_embed,
                                         query_embed, out, qb);

    dim3 ggrid(M / TM, E_ / TN);
    for (int l = 0; l < L_; ++l) {
        const float* wq = Wq + (size_t)l * E_ * E_;
        const float* wk = Wk + (size_t)l * E_ * E_;
        const float* wv = Wv + (size_t)l * E_ * E_;
        const float* wo = Wo + (size_t)l * E_ * E_;
        gemm_kernel<0><<<ggrid, 256, 0, stream>>>(qb,  wq, bq + l * E_, Qb, M, E_, E_);
        gemm_kernel<0><<<ggrid, 256, 0, stream>>>(out, wk, bk + l * E_, Kb, M, E_, E_);
        gemm_kernel<0><<<ggrid, 256, 0, stream>>>(out, wv, bv + l * E_, Vb, M, E_, E_);
        attn_mfma_kernel<<<B_ * H_ * (S_ / 64), 256, 0, stream>>>(
            Qb, Kb, Vb, pos_key, pos_value, mg);
        gemm_kernel<1><<<ggrid, 256, 0, stream>>>(mg, wo, bo + l * E_, out, M, E_, E_);
    }

    final_kernel<<<M, 256, 0, stream>>>(out, out_w, out_b, y);
}

// Round 3
// 130.372 us; speedup vs baseline: 10.7799x; 1.7327x over previous
//
#include <hip/hip_runtime.h>
#include <hip/hip_bf16.h>

#define B_ 16
#define S_ 512
#define E_ 256
#define H_ 4
#define D_ 64
#define L_ 2
#define MAXPOS 10

typedef __attribute__((ext_vector_type(8))) short bf16x8;
typedef __attribute__((ext_vector_type(4))) float f32x4;

static __device__ __forceinline__ short f2bf(float f) {
    __hip_bfloat16 h = __float2bfloat16(f);
    return __builtin_bit_cast(short, h);
}

// ---------------- prep: Wt[m][n][k] = bf16(W[m][k][n]) for m = (l*4 + {q,k,v,o});
// pkb[16][64] = bf16(pos_key) zero-padded to 16 rows.
__global__ __launch_bounds__(256) void prep_kernel(
    const float* __restrict__ Wq, const float* __restrict__ Wk,
    const float* __restrict__ Wv, const float* __restrict__ Wo,
    const float* __restrict__ pos_key, short* __restrict__ Wt,
    short* __restrict__ pkb)
{
    __shared__ short tt[64 * 72];
    const int tid = threadIdx.x;
    if (blockIdx.x < 128) {
        const int mId = blockIdx.x >> 4;
        const int l = mId >> 2, which = mId & 3;
        const float* src = (which == 0 ? Wq : which == 1 ? Wk : which == 2 ? Wv : Wo)
                         + (size_t)l * E_ * E_;
        const int tr = (blockIdx.x >> 2) & 3;   // k-tile
        const int tc = blockIdx.x & 3;          // n-tile
        {
            const int kl = tid >> 2;
            const int nq = (tid & 3) * 16;
            const float* sp = src + (size_t)(tr * 64 + kl) * E_ + tc * 64 + nq;
            #pragma unroll
            for (int q = 0; q < 4; ++q) {
                const float4 v = reinterpret_cast<const float4*>(sp)[q];
                tt[(nq + q * 4 + 0) * 72 + kl] = f2bf(v.x);
                tt[(nq + q * 4 + 1) * 72 + kl] = f2bf(v.y);
                tt[(nq + q * 4 + 2) * 72 + kl] = f2bf(v.z);
                tt[(nq + q * 4 + 3) * 72 + kl] = f2bf(v.w);
            }
        }
        __syncthreads();
        {
            const int nl = tid >> 2;
            const int kq = (tid & 3) * 16;
            short* dst = Wt + (size_t)mId * 65536 + (size_t)(tc * 64 + nl) * E_ + tr * 64 + kq;
            *reinterpret_cast<bf16x8*>(&dst[0]) = *reinterpret_cast<const bf16x8*>(&tt[nl * 72 + kq]);
            *reinterpret_cast<bf16x8*>(&dst[8]) = *reinterpret_cast<const bf16x8*>(&tt[nl * 72 + kq + 8]);
        }
    } else {
        for (int idx = tid; idx < 16 * 64; idx += 256) {
            const int r = idx >> 6, d = idx & 63;
            pkb[idx] = (r < MAXPOS) ? f2bf(pos_key[r * 64 + d]) : (short)0;
        }
    }
}

// ---------------- gather: out_f32/out_bf16 = input_embed[item_inputs], qb_bf16 = query_embed[item_ids]
__global__ __launch_bounds__(256) void gather_kernel(
    const int* __restrict__ item_inputs, const int* __restrict__ item_ids,
    const float* __restrict__ input_embed, const float* __restrict__ query_embed,
    float* __restrict__ outf, short* __restrict__ outb, short* __restrict__ qbb)
{
    const int row = blockIdx.x;
    const int e = threadIdx.x;
    const int ii = item_inputs[row];
    const int qi = item_ids[row];
    const float xv = input_embed[(size_t)ii * E_ + e];
    const float qv = query_embed[(size_t)qi * E_ + e];
    const size_t idx = (size_t)row * E_ + e;
    outf[idx] = xv;
    outb[idx] = f2bf(xv);
    qbb[idx] = f2bf(qv);
}

// ---------------- bf16 MFMA GEMM, full K=256 in LDS.
// MODE 0 (QKV fused, gridDim.z=3): C[z] = A[z] @ Wt[z] + bias[z], bf16 out.
// MODE 1 (O-proj): outf += relu(A @ Wt + bias); outb = bf16(outf).
template<int MODE>
__global__ __launch_bounds__(256) void mfma_gemm_kernel(
    const short* __restrict__ Aq, const short* __restrict__ Akv,
    const short* __restrict__ Wt, const float* __restrict__ b0,
    const float* __restrict__ b1, const float* __restrict__ b2,
    short* __restrict__ C, float* __restrict__ outf, short* __restrict__ outb)
{
    __shared__ short As[64 * 264];
    __shared__ short Bs[64 * 264];
    const int bm = blockIdx.x, bn = blockIdx.y, z = blockIdx.z;
    const int tid = threadIdx.x;
    const int lane = tid & 63, w = tid >> 6;
    const int l15 = lane & 15, l4 = lane >> 4;

    const short* A;
    const short* W;
    const float* bias;
    if (MODE == 0) {
        A = (z == 0) ? Aq : Akv;
        W = Wt + (size_t)z * 65536;
        bias = (z == 0) ? b0 : (z == 1) ? b1 : b2;
    } else {
        A = Aq; W = Wt; bias = b0;
    }

    {
        const int r = tid >> 2, kq = (tid & 3) * 64;
        const short* ap = A + (size_t)(bm * 64 + r) * E_ + kq;
        const short* wp = W + (size_t)(bn * 64 + r) * E_ + kq;
        #pragma unroll
        for (int i = 0; i < 8; ++i) {
            *reinterpret_cast<bf16x8*>(&As[r * 264 + kq + i * 8]) =
                *reinterpret_cast<const bf16x8*>(&ap[i * 8]);
            *reinterpret_cast<bf16x8*>(&Bs[r * 264 + kq + i * 8]) =
                *reinterpret_cast<const bf16x8*>(&wp[i * 8]);
        }
    }
    __syncthreads();

    f32x4 acc[4];
    #pragma unroll
    for (int nf = 0; nf < 4; ++nf) acc[nf] = (f32x4){0.f, 0.f, 0.f, 0.f};

    #pragma unroll
    for (int ks = 0; ks < 8; ++ks) {
        const bf16x8 af = *reinterpret_cast<const bf16x8*>(
            &As[(w * 16 + l15) * 264 + ks * 32 + l4 * 8]);
        #pragma unroll
        for (int nf = 0; nf < 4; ++nf) {
            const bf16x8 bfr = *reinterpret_cast<const bf16x8*>(
                &Bs[(nf * 16 + l15) * 264 + ks * 32 + l4 * 8]);
            acc[nf] = __builtin_amdgcn_mfma_f32_16x16x32_bf16(af, bfr, acc[nf], 0, 0, 0);
        }
    }

    short* Cz = (MODE == 0) ? C + (size_t)z * ((size_t)B_ * S_ * E_) : nullptr;
    #pragma unroll
    for (int nf = 0; nf < 4; ++nf) {
        const int col = bn * 64 + nf * 16 + l15;
        const float bb = bias[col];
        #pragma unroll
        for (int reg = 0; reg < 4; ++reg) {
            const int rowg = bm * 64 + w * 16 + l4 * 4 + reg;
            const float v = acc[nf][reg] + bb;
            const size_t idx = (size_t)rowg * E_ + col;
            if (MODE == 0) {
                Cz[idx] = f2bf(v);
            } else {
                const float o = outf[idx] + fmaxf(v, 0.0f);
                outf[idx] = o;
                outb[idx] = f2bf(o);
            }
        }
    }
}

// ---------------- flash-style MFMA attention (bf16 in/out)
__global__ __launch_bounds__(256) void attn_mfma_kernel(
    const short* __restrict__ Q, const short* __restrict__ K,
    const short* __restrict__ V, const short* __restrict__ pkb,
    const float* __restrict__ pos_value, short* __restrict__ merged)
{
    __shared__ short Qs[64 * 72];
    __shared__ short Ks[64 * 72];
    __shared__ short Vts[64 * 72];
    __shared__ short Pl[4 * 16 * 72];
    __shared__ short Pk[16 * 72];
    __shared__ float pv_sh[MAXPOS * 64];
    __shared__ float qpk_sh[64 * 16];
    __shared__ float pdiag[64 * 9];

    const int bid = blockIdx.x;
    const int it = 7 - (bid & 7);       // big tiles dispatch first
    const int h  = (bid >> 3) & 3;
    const int b  = bid >> 5;
    const int tid = threadIdx.x;
    const int lane = tid & 63;
    const int w = tid >> 6;
    const int l15 = lane & 15;
    const int l4  = lane >> 4;
    const int rloc  = l4 * 4;
    const int rbase = w * 16 + rloc;

    const size_t boff = (size_t)(b * S_) * E_ + h * D_;

    for (int idx = tid; idx < MAXPOS * 64; idx += 256) pv_sh[idx] = pos_value[idx];
    for (int idx = tid; idx < 64 * 9; idx += 256) pdiag[idx] = 0.0f;
    if (tid < 128) {
        const int r = tid >> 3, dq = (tid & 7) * 8;
        *reinterpret_cast<bf16x8*>(&Pk[r * 72 + dq]) =
            *reinterpret_cast<const bf16x8*>(&pkb[r * 64 + dq]);
    }
    {
        const int row = tid >> 2, dq = (tid & 3) * 16;
        const short* qp = &Q[boff + (size_t)(it * 64 + row) * E_ + dq];
        *reinterpret_cast<bf16x8*>(&Qs[row * 72 + dq]) =
            *reinterpret_cast<const bf16x8*>(qp);
        *reinterpret_cast<bf16x8*>(&Qs[row * 72 + dq + 8]) =
            *reinterpret_cast<const bf16x8*>(qp + 8);
    }
    __syncthreads();

    bf16x8 aq[2];
    #pragma unroll
    for (int ks = 0; ks < 2; ++ks)
        aq[ks] = *reinterpret_cast<const bf16x8*>(
            &Qs[(w * 16 + l15) * 72 + ks * 32 + 8 * l4]);

    // qpk[row][rel] = Q @ pk^T via 2 MFMAs (cols 10..15 hit zero pk rows)
    f32x4 cq = (f32x4){0.f, 0.f, 0.f, 0.f};
    #pragma unroll
    for (int ks = 0; ks < 2; ++ks) {
        const bf16x8 bpk = *reinterpret_cast<const bf16x8*>(
            &Pk[l15 * 72 + ks * 32 + 8 * l4]);
        cq = __builtin_amdgcn_mfma_f32_16x16x32_bf16(aq[ks], bpk, cq, 0, 0, 0);
    }
    float q9[4];
    #pragma unroll
    for (int r = 0; r < 4; ++r) {
        qpk_sh[(rbase + r) * 16 + l15] = cq[r];
        q9[r] = __shfl(cq[r], l4 * 16 + 9, 64);
    }

    f32x4 accv[4];
    #pragma unroll
    for (int nf = 0; nf < 4; ++nf) accv[nf] = (f32x4){0.f, 0.f, 0.f, 0.f};
    float ls[4] = {0.f, 0.f, 0.f, 0.f};

    for (int jt = 0; jt <= it; ++jt) {
        {
            const int row = tid >> 2, dq = (tid & 3) * 16;
            const short* kp = &K[boff + (size_t)(jt * 64 + row) * E_ + dq];
            const short* vp = &V[boff + (size_t)(jt * 64 + row) * E_ + dq];
            const bf16x8 k0 = *reinterpret_cast<const bf16x8*>(kp);
            const bf16x8 k1 = *reinterpret_cast<const bf16x8*>(kp + 8);
            const bf16x8 v0 = *reinterpret_cast<const bf16x8*>(vp);
            const bf16x8 v1 = *reinterpret_cast<const bf16x8*>(vp + 8);
            *reinterpret_cast<bf16x8*>(&Ks[row * 72 + dq]) = k0;
            *reinterpret_cast<bf16x8*>(&Ks[row * 72 + dq + 8]) = k1;
            #pragma unroll
            for (int e = 0; e < 8; ++e) {
                Vts[(dq + e) * 72 + row] = v0[e];
                Vts[(dq + 8 + e) * 72 + row] = v1[e];
            }
        }
        __syncthreads();

        const bool near = (jt >= it - 1);
        #pragma unroll
        for (int nf = 0; nf < 4; ++nf) {
            f32x4 c = (f32x4){0.f, 0.f, 0.f, 0.f};
            const bf16x8 bk0 = *reinterpret_cast<const bf16x8*>(
                &Ks[(nf * 16 + l15) * 72 + 8 * l4]);
            const bf16x8 bk1 = *reinterpret_cast<const bf16x8*>(
                &Ks[(nf * 16 + l15) * 72 + 32 + 8 * l4]);
            c = __builtin_amdgcn_mfma_f32_16x16x32_bf16(aq[0], bk0, c, 0, 0, 0);
            c = __builtin_amdgcn_mfma_f32_16x16x32_bf16(aq[1], bk1, c, 0, 0, 0);
            const int j = jt * 64 + nf * 16 + l15;
            #pragma unroll
            for (int r = 0; r < 4; ++r) {
                float p;
                if (near) {
                    const int i = it * 64 + rbase + r;
                    const int rel = i - j;
                    if (rel < 0) p = 0.0f;
                    else {
                        const int rc = rel < 9 ? rel : 9;
                        p = __expf((c[r] + qpk_sh[(rbase + r) * 16 + rc]) * 0.125f);
                        if (rel < 9) pdiag[(rbase + r) * 9 + rel] = p;
                    }
                } else {
                    p = __expf((c[r] + q9[r]) * 0.125f);
                }
                ls[r] += p;
                Pl[w * 1152 + (rloc + r) * 72 + nf * 16 + l15] = f2bf(p);
            }
        }
        // no barrier: Pl + pdiag are intra-wave; Vts staged before the last barrier
        #pragma unroll
        for (int ks = 0; ks < 2; ++ks) {
            const bf16x8 pa = *reinterpret_cast<const bf16x8*>(
                &Pl[w * 1152 + l15 * 72 + ks * 32 + 8 * l4]);
            #pragma unroll
            for (int nf = 0; nf < 4; ++nf) {
                const bf16x8 bv = *reinterpret_cast<const bf16x8*>(
                    &Vts[(nf * 16 + l15) * 72 + ks * 32 + 8 * l4]);
                accv[nf] = __builtin_amdgcn_mfma_f32_16x16x32_bf16(pa, bv, accv[nf], 0, 0, 0);
            }
        }
        __syncthreads();
    }

    #pragma unroll
    for (int m = 1; m < 16; m <<= 1) {
        #pragma unroll
        for (int r = 0; r < 4; ++r) ls[r] += __shfl_xor(ls[r], m, 64);
    }

    #pragma unroll
    for (int r = 0; r < 4; ++r) {
        const int rowl = rbase + r;
        const float inv = 1.0f / ls[r];
        #pragma unroll
        for (int nf = 0; nf < 4; ++nf) {
            const int col = nf * 16 + l15;
            const float pv9 = pv_sh[9 * 64 + col];
            float extra = ls[r] * pv9;
            #pragma unroll
            for (int rr = 0; rr < 9; ++rr)
                extra += pdiag[rowl * 9 + rr] * (pv_sh[rr * 64 + col] - pv9);
            merged[boff + (size_t)(it * 64 + rowl) * E_ + col] =
                f2bf((accv[nf][r] + extra) * inv);
        }
    }
}

// ---------------- final: one wave per row
__global__ __launch_bounds__(256) void final_kernel(
    const float* __restrict__ x, const float* __restrict__ w,
    const float* __restrict__ b, float* __restrict__ y)
{
    const int row = blockIdx.x * 4 + (threadIdx.x >> 6);
    const int lane = threadIdx.x & 63;
    const float4 v = *reinterpret_cast<const float4*>(&x[(size_t)row * E_ + lane * 4]);
    const float4 wv = *reinterpret_cast<const float4*>(&w[lane * 4]);
    float s = v.x * wv.x + v.y * wv.y + v.z * wv.z + v.w * wv.w;
    #pragma unroll
    for (int m = 1; m < 64; m <<= 1) s += __shfl_xor(s, m, 64);
    if (lane == 0) y[row] = s + b[0];
}

extern "C" void kernel_launch(void* const* d_in, const int* in_sizes, int n_in,
                              void* d_out, int out_size, void* d_ws, size_t ws_size,
                              hipStream_t stream) {
    const int*   item_inputs = (const int*)d_in[0];
    const int*   item_ids    = (const int*)d_in[1];
    const float* input_embed = (const float*)d_in[2];
    const float* query_embed = (const float*)d_in[3];
    const float* pos_key     = (const float*)d_in[4];
    const float* pos_value   = (const float*)d_in[5];
    const float* Wq = (const float*)d_in[6];
    const float* bq = (const float*)d_in[7];
    const float* Wk = (const float*)d_in[8];
    const float* bk = (const float*)d_in[9];
    const float* Wv = (const float*)d_in[10];
    const float* bv = (const float*)d_in[11];
    const float* Wo = (const float*)d_in[12];
    const float* bo = (const float*)d_in[13];
    const float* out_w = (const float*)d_in[14];
    const float* out_b = (const float*)d_in[15];
    float* y = (float*)d_out;

    char* w8 = (char*)d_ws;
    float* outf = (float*)(w8);                          // 8 MB f32 hidden
    short* outb = (short*)(w8 + ((size_t)8  << 20));     // 4 MB bf16 hidden
    short* qbb  = (short*)(w8 + ((size_t)12 << 20));     // 4 MB bf16 q-base
    short* Qb   = (short*)(w8 + ((size_t)16 << 20));     // 12 MB bf16 Q,K,V
    short* mgb  = (short*)(w8 + ((size_t)28 << 20));     // 4 MB bf16 merged
    short* Wt   = (short*)(w8 + ((size_t)32 << 20));     // 1 MB bf16 weights^T
    short* pkb  = (short*)(w8 + ((size_t)33 << 20));     // 2 KB bf16 pos_key

    const size_t HS = (size_t)B_ * S_ * E_;  // 2097152

    prep_kernel<<<129, 256, 0, stream>>>(Wq, Wk, Wv, Wo, pos_key, Wt, pkb);
    gather_kernel<<<B_ * S_, 256, 0, stream>>>(item_inputs, item_ids, input_embed,
                                               query_embed, outf, outb, qbb);

    for (int l = 0; l < L_; ++l) {
        mfma_gemm_kernel<0><<<dim3(128, 4, 3), 256, 0, stream>>>(
            qbb, outb, Wt + (size_t)l * 262144,
            bq + l * E_, bk + l * E_, bv + l * E_, Qb, nullptr, nullptr);
        attn_mfma_kernel<<<B_ * H_ * (S_ / 64), 256, 0, stream>>>(
            Qb, Qb + HS, Qb + 2 * HS, pkb, pos_value, mgb);
        mfma_gemm_kernel<1><<<dim3(128, 4, 1), 256, 0, stream>>>(
            mgb, nullptr, Wt + (size_t)l * 262144 + 3 * 65536,
            bo + l * E_, nullptr, nullptr, nullptr, outf, outb);
    }

    final_kernel<<<(B_ * S_) / 4, 256, 0, stream>>>(outf, out_w, out_b, y);
}

// Round 4
// 100.708 us; speedup vs baseline: 13.9551x; 1.2946x over previous
//
#include <hip/hip_runtime.h>
#include <hip/hip_bf16.h>

#define B_ 16
#define S_ 512
#define E_ 256
#define H_ 4
#define D_ 64
#define L_ 2
#define MAXPOS 10

typedef __attribute__((ext_vector_type(8))) short bf16x8;
typedef __attribute__((ext_vector_type(4))) float f32x4;

static __device__ __forceinline__ short f2bf(float f) {
    __hip_bfloat16 h = __float2bfloat16(f);
    return __builtin_bit_cast(short, h);
}

static __device__ __forceinline__ void gload16(const void* g, void* l) {
    __builtin_amdgcn_global_load_lds(
        (const __attribute__((address_space(1))) void*)(g),
        (__attribute__((address_space(3))) void*)(l),
        16, 0, 0);
}

// ---------------- setup: gather + weight transpose + pos_key pad + y init
// blocks [0,8192): gather row; [8192,8320): Wt tile; 8320: pkb; 8321: y init.
__global__ __launch_bounds__(256) void setup_kernel(
    const int* __restrict__ item_inputs, const int* __restrict__ item_ids,
    const float* __restrict__ input_embed, const float* __restrict__ query_embed,
    const float* __restrict__ Wq, const float* __restrict__ Wk,
    const float* __restrict__ Wv, const float* __restrict__ Wo,
    const float* __restrict__ pos_key, const float* __restrict__ out_b,
    float* __restrict__ outf, short* __restrict__ outb, short* __restrict__ qbb,
    short* __restrict__ Wt, short* __restrict__ pkb, float* __restrict__ y)
{
    const int tid = threadIdx.x;
    const int bx = blockIdx.x;
    if (bx < 8192) {
        const int row = bx;
        const int ii = item_inputs[row];
        const int qi = item_ids[row];
        const float xv = input_embed[(size_t)ii * E_ + tid];
        const float qv = query_embed[(size_t)qi * E_ + tid];
        const size_t idx = (size_t)row * E_ + tid;
        outf[idx] = xv;
        outb[idx] = f2bf(xv);
        qbb[idx] = f2bf(qv);
        return;
    }
    const int pb = bx - 8192;
    if (pb < 128) {
        __shared__ short tt[64 * 72];
        const int mId = pb >> 4;
        const int l = mId >> 2, which = mId & 3;
        const float* src = (which == 0 ? Wq : which == 1 ? Wk : which == 2 ? Wv : Wo)
                         + (size_t)l * E_ * E_;
        const int tr = (pb >> 2) & 3;
        const int tc = pb & 3;
        {
            const int kl = tid >> 2;
            const int nq = (tid & 3) * 16;
            const float* sp = src + (size_t)(tr * 64 + kl) * E_ + tc * 64 + nq;
            #pragma unroll
            for (int q = 0; q < 4; ++q) {
                const float4 v = reinterpret_cast<const float4*>(sp)[q];
                tt[(nq + q * 4 + 0) * 72 + kl] = f2bf(v.x);
                tt[(nq + q * 4 + 1) * 72 + kl] = f2bf(v.y);
                tt[(nq + q * 4 + 2) * 72 + kl] = f2bf(v.z);
                tt[(nq + q * 4 + 3) * 72 + kl] = f2bf(v.w);
            }
        }
        __syncthreads();
        {
            const int nl = tid >> 2;
            const int kq = (tid & 3) * 16;
            short* dst = Wt + (size_t)mId * 65536 + (size_t)(tc * 64 + nl) * E_ + tr * 64 + kq;
            *reinterpret_cast<bf16x8*>(&dst[0]) = *reinterpret_cast<const bf16x8*>(&tt[nl * 72 + kq]);
            *reinterpret_cast<bf16x8*>(&dst[8]) = *reinterpret_cast<const bf16x8*>(&tt[nl * 72 + kq + 8]);
        }
    } else if (pb == 128) {
        for (int idx = tid; idx < 16 * 64; idx += 256) {
            const int r = idx >> 6, d = idx & 63;
            pkb[idx] = (r < MAXPOS) ? f2bf(pos_key[r * 64 + d]) : (short)0;
        }
    } else {
        const float yb = out_b[0];
        for (int i = tid; i < 8192; i += 256) y[i] = yb;
    }
}

// ---------------- bf16 MFMA GEMM, full K=256 in LDS, global_load_lds + XOR swizzle.
// MODE 0 (QKV fused, gridDim.z=3): C[z] = A[z] @ Wt[z] + bias[z], bf16 out.
// MODE 1 (O-proj): outf += relu(A @ Wt + bias); outb = bf16(outf).
// FINAL 1: also y[row] += dot(outf_row_cols, fw) via wave-reduced atomics.
template<int MODE, int FINAL>
__global__ __launch_bounds__(256) void mfma_gemm_kernel(
    const short* __restrict__ Aq, const short* __restrict__ Akv,
    const short* __restrict__ Wt, const float* __restrict__ b0,
    const float* __restrict__ b1, const float* __restrict__ b2,
    short* __restrict__ C, float* __restrict__ outf, short* __restrict__ outb,
    const float* __restrict__ fw, float* __restrict__ y)
{
    __shared__ __align__(16) short As[64 * 256];
    __shared__ __align__(16) short Bs[64 * 256];
    const int bm = blockIdx.x, bn = blockIdx.y, z = blockIdx.z;
    const int tid = threadIdx.x;
    const int lane = tid & 63, w = tid >> 6;
    const int l15 = lane & 15, l4 = lane >> 4;

    const short* A;
    const short* W;
    const float* bias;
    if (MODE == 0) {
        A = (z == 0) ? Aq : Akv;
        W = Wt + (size_t)z * 65536;
        bias = (z == 0) ? b0 : (z == 1) ? b1 : b2;
    } else {
        A = Aq; W = Wt; bias = b0;
    }

    // stage A,B tiles (each 32 KB contiguous in global) via global_load_lds,
    // source pre-swizzled so LDS holds lds[row*512+c] = g[row*512 + (c^((row&7)<<4))]
    {
        const char* Ab = (const char*)A + (size_t)bm * 64 * 512;
        const char* Wb = (const char*)W + (size_t)bn * 64 * 512;
        #pragma unroll
        for (int c = 0; c < 8; ++c) {
            const int L = (w * 8 + c) * 1024 + lane * 16;
            const int src = L ^ (((L >> 9) & 7) << 4);
            gload16(Ab + src, (char*)As + (w * 8 + c) * 1024);
            gload16(Wb + src, (char*)Bs + (w * 8 + c) * 1024);
        }
    }
    __syncthreads();

    f32x4 acc[4];
    #pragma unroll
    for (int nf = 0; nf < 4; ++nf) acc[nf] = (f32x4){0.f, 0.f, 0.f, 0.f};

    const int sw = (l15 & 7) << 4;
    const int arow = w * 16 + l15;
    #pragma unroll
    for (int ks = 0; ks < 8; ++ks) {
        const int coff = (ks * 64 + l4 * 16) ^ sw;
        const bf16x8 af = *reinterpret_cast<const bf16x8*>(
            (const char*)As + arow * 512 + coff);
        #pragma unroll
        for (int nf = 0; nf < 4; ++nf) {
            const bf16x8 bfr = *reinterpret_cast<const bf16x8*>(
                (const char*)Bs + (nf * 16 + l15) * 512 + coff);
            acc[nf] = __builtin_amdgcn_mfma_f32_16x16x32_bf16(af, bfr, acc[nf], 0, 0, 0);
        }
    }

    short* Cz = (MODE == 0) ? C + (size_t)z * ((size_t)B_ * S_ * E_) : nullptr;
    float s[4] = {0.f, 0.f, 0.f, 0.f};
    #pragma unroll
    for (int nf = 0; nf < 4; ++nf) {
        const int col = bn * 64 + nf * 16 + l15;
        const float bb = bias[col];
        const float fwv = FINAL ? fw[col] : 0.0f;
        #pragma unroll
        for (int reg = 0; reg < 4; ++reg) {
            const int rowg = bm * 64 + w * 16 + l4 * 4 + reg;
            const float v = acc[nf][reg] + bb;
            const size_t idx = (size_t)rowg * E_ + col;
            if (MODE == 0) {
                Cz[idx] = f2bf(v);
            } else {
                const float o = outf[idx] + fmaxf(v, 0.0f);
                outf[idx] = o;
                outb[idx] = f2bf(o);
                if (FINAL) s[reg] += o * fwv;
            }
        }
    }
    if (FINAL) {
        #pragma unroll
        for (int m = 1; m < 16; m <<= 1) {
            #pragma unroll
            for (int reg = 0; reg < 4; ++reg) s[reg] += __shfl_xor(s[reg], m, 64);
        }
        if (l15 == 0) {
            #pragma unroll
            for (int reg = 0; reg < 4; ++reg)
                atomicAdd(&y[bm * 64 + w * 16 + l4 * 4 + reg], s[reg]);
        }
    }
}

// ---------------- flash-style MFMA attention (bf16 in/out)
// K staged by global_load_lds into swizzled linear [64][64]; V reg-transposed
// into skewed LDS (addr = d*144 + (d>>4)*32 + j*2) -> conflict-free writes.
__global__ __launch_bounds__(256) void attn_mfma_kernel(
    const short* __restrict__ Q, const short* __restrict__ K,
    const short* __restrict__ V, const short* __restrict__ pkb,
    const float* __restrict__ pos_value, short* __restrict__ merged)
{
    __shared__ __align__(16) short Qs[64 * 72];
    __shared__ __align__(16) short Ks[64 * 64];
    __shared__ __align__(16) short Vts[4656];
    __shared__ __align__(16) short Pl[4 * 16 * 72];
    __shared__ __align__(16) short Pk[16 * 72];
    __shared__ float pv_sh[MAXPOS * 64];
    __shared__ float qpk_sh[64 * 16];
    __shared__ float pdiag[64 * 9];

    const int bid = blockIdx.x;
    const int it = 7 - (bid & 7);
    const int h  = (bid >> 3) & 3;
    const int b  = bid >> 5;
    const int tid = threadIdx.x;
    const int lane = tid & 63;
    const int w = tid >> 6;
    const int l15 = lane & 15;
    const int l4  = lane >> 4;
    const int rloc  = l4 * 4;
    const int rbase = w * 16 + rloc;

    const size_t boff = (size_t)(b * S_) * E_ + h * D_;

    for (int idx = tid; idx < MAXPOS * 64; idx += 256) pv_sh[idx] = pos_value[idx];
    for (int idx = tid; idx < 64 * 9; idx += 256) pdiag[idx] = 0.0f;
    if (tid < 128) {
        const int r = tid >> 3, dq = (tid & 7) * 8;
        *reinterpret_cast<bf16x8*>(&Pk[r * 72 + dq]) =
            *reinterpret_cast<const bf16x8*>(&pkb[r * 64 + dq]);
    }
    {
        const int row = tid >> 2, dq = (tid & 3) * 16;
        const short* qp = &Q[boff + (size_t)(it * 64 + row) * E_ + dq];
        *reinterpret_cast<bf16x8*>(&Qs[row * 72 + dq]) =
            *reinterpret_cast<const bf16x8*>(qp);
        *reinterpret_cast<bf16x8*>(&Qs[row * 72 + dq + 8]) =
            *reinterpret_cast<const bf16x8*>(qp + 8);
    }
    __syncthreads();

    bf16x8 aq[2];
    #pragma unroll
    for (int ks = 0; ks < 2; ++ks)
        aq[ks] = *reinterpret_cast<const bf16x8*>(
            &Qs[(w * 16 + l15) * 72 + ks * 32 + 8 * l4]);

    f32x4 cq = (f32x4){0.f, 0.f, 0.f, 0.f};
    #pragma unroll
    for (int ks = 0; ks < 2; ++ks) {
        const bf16x8 bpk = *reinterpret_cast<const bf16x8*>(
            &Pk[l15 * 72 + ks * 32 + 8 * l4]);
        cq = __builtin_amdgcn_mfma_f32_16x16x32_bf16(aq[ks], bpk, cq, 0, 0, 0);
    }
    float q9[4];
    #pragma unroll
    for (int r = 0; r < 4; ++r) {
        qpk_sh[(rbase + r) * 16 + l15] = cq[r];
        q9[r] = __shfl(cq[r], l4 * 16 + 9, 64);
    }

    f32x4 accv[4];
    #pragma unroll
    for (int nf = 0; nf < 4; ++nf) accv[nf] = (f32x4){0.f, 0.f, 0.f, 0.f};
    float ls[4] = {0.f, 0.f, 0.f, 0.f};

    const int swl = (l15 & 7) << 4;

    for (int jt = 0; jt <= it; ++jt) {
        // ---- stage K (gload, swizzled) and V (reg transpose, skewed)
        {
            const char* Kb = (const char*)(K + boff + (size_t)(jt * 64) * E_);
            #pragma unroll
            for (int c = 0; c < 2; ++c) {
                const int chunk = w * 2 + c;
                const int row = chunk * 8 + (lane >> 3);
                const int col = (lane & 7) * 16;
                const int src = row * 512 + (col ^ ((row & 7) << 4));
                gload16(Kb + src, (char*)Ks + chunk * 1024);
            }
            const int row = tid >> 2, dq = (tid & 3) * 16;
            const short* vp = &V[boff + (size_t)(jt * 64 + row) * E_ + dq];
            const bf16x8 v0 = *reinterpret_cast<const bf16x8*>(vp);
            const bf16x8 v1 = *reinterpret_cast<const bf16x8*>(vp + 8);
            const int skew = (tid & 3) * 32 + row * 2;
            #pragma unroll
            for (int e = 0; e < 8; ++e) {
                *(short*)((char*)Vts + (dq + e) * 144 + skew) = v0[e];
                *(short*)((char*)Vts + (dq + 8 + e) * 144 + skew) = v1[e];
            }
        }
        __syncthreads();

        const bool near = (jt >= it - 1);
        #pragma unroll
        for (int nf = 0; nf < 4; ++nf) {
            f32x4 c = (f32x4){0.f, 0.f, 0.f, 0.f};
            const int jrow = nf * 16 + l15;
            const bf16x8 bk0 = *reinterpret_cast<const bf16x8*>(
                (const char*)Ks + jrow * 128 + ((l4 * 16) ^ swl));
            const bf16x8 bk1 = *reinterpret_cast<const bf16x8*>(
                (const char*)Ks + jrow * 128 + ((64 + l4 * 16) ^ swl));
            c = __builtin_amdgcn_mfma_f32_16x16x32_bf16(aq[0], bk0, c, 0, 0, 0);
            c = __builtin_amdgcn_mfma_f32_16x16x32_bf16(aq[1], bk1, c, 0, 0, 0);
            const int j = jt * 64 + nf * 16 + l15;
            #pragma unroll
            for (int r = 0; r < 4; ++r) {
                float p;
                if (near) {
                    const int i = it * 64 + rbase + r;
                    const int rel = i - j;
                    if (rel < 0) p = 0.0f;
                    else {
                        const int rc = rel < 9 ? rel : 9;
                        p = __expf((c[r] + qpk_sh[(rbase + r) * 16 + rc]) * 0.125f);
                        if (rel < 9) pdiag[(rbase + r) * 9 + rel] = p;
                    }
                } else {
                    p = __expf((c[r] + q9[r]) * 0.125f);
                }
                ls[r] += p;
                Pl[w * 1152 + (rloc + r) * 72 + nf * 16 + l15] = f2bf(p);
            }
        }
        // Pl + pdiag are intra-wave; Vts/Ks protected by the loop-end barrier
        #pragma unroll
        for (int ks = 0; ks < 2; ++ks) {
            const bf16x8 pa = *reinterpret_cast<const bf16x8*>(
                &Pl[w * 1152 + l15 * 72 + ks * 32 + 8 * l4]);
            #pragma unroll
            for (int nf = 0; nf < 4; ++nf) {
                const int d = nf * 16 + l15;
                const bf16x8 bv = *reinterpret_cast<const bf16x8*>(
                    (const char*)Vts + d * 144 + nf * 32 + ks * 64 + l4 * 16);
                accv[nf] = __builtin_amdgcn_mfma_f32_16x16x32_bf16(pa, bv, accv[nf], 0, 0, 0);
            }
        }
        __syncthreads();
    }

    #pragma unroll
    for (int m = 1; m < 16; m <<= 1) {
        #pragma unroll
        for (int r = 0; r < 4; ++r) ls[r] += __shfl_xor(ls[r], m, 64);
    }

    #pragma unroll
    for (int r = 0; r < 4; ++r) {
        const int rowl = rbase + r;
        const float inv = 1.0f / ls[r];
        #pragma unroll
        for (int nf = 0; nf < 4; ++nf) {
            const int col = nf * 16 + l15;
            const float pv9 = pv_sh[9 * 64 + col];
            float extra = ls[r] * pv9;
            #pragma unroll
            for (int rr = 0; rr < 9; ++rr)
                extra += pdiag[rowl * 9 + rr] * (pv_sh[rr * 64 + col] - pv9);
            merged[boff + (size_t)(it * 64 + rowl) * E_ + col] =
                f2bf((accv[nf][r] + extra) * inv);
        }
    }
}

extern "C" void kernel_launch(void* const* d_in, const int* in_sizes, int n_in,
                              void* d_out, int out_size, void* d_ws, size_t ws_size,
                              hipStream_t stream) {
    const int*   item_inputs = (const int*)d_in[0];
    const int*   item_ids    = (const int*)d_in[1];
    const float* input_embed = (const float*)d_in[2];
    const float* query_embed = (const float*)d_in[3];
    const float* pos_key     = (const float*)d_in[4];
    const float* pos_value   = (const float*)d_in[5];
    const float* Wq = (const float*)d_in[6];
    const float* bq = (const float*)d_in[7];
    const float* Wk = (const float*)d_in[8];
    const float* bk = (const float*)d_in[9];
    const float* Wv = (const float*)d_in[10];
    const float* bv = (const float*)d_in[11];
    const float* Wo = (const float*)d_in[12];
    const float* bo = (const float*)d_in[13];
    const float* out_w = (const float*)d_in[14];
    const float* out_b = (const float*)d_in[15];
    float* y = (float*)d_out;

    char* w8 = (char*)d_ws;
    float* outf = (float*)(w8);                          // 8 MB f32 hidden
    short* outb = (short*)(w8 + ((size_t)8  << 20));     // 4 MB bf16 hidden
    short* qbb  = (short*)(w8 + ((size_t)12 << 20));     // 4 MB bf16 q-base
    short* Qb   = (short*)(w8 + ((size_t)16 << 20));     // 12 MB bf16 Q,K,V
    short* mgb  = (short*)(w8 + ((size_t)28 << 20));     // 4 MB bf16 merged
    short* Wt   = (short*)(w8 + ((size_t)32 << 20));     // 1 MB bf16 weights^T
    short* pkb  = (short*)(w8 + ((size_t)33 << 20));     // 2 KB bf16 pos_key

    const size_t HS = (size_t)B_ * S_ * E_;

    setup_kernel<<<8192 + 130, 256, 0, stream>>>(
        item_inputs, item_ids, input_embed, query_embed,
        Wq, Wk, Wv, Wo, pos_key, out_b, outf, outb, qbb, Wt, pkb, y);

    for (int l = 0; l < L_; ++l) {
        mfma_gemm_kernel<0, 0><<<dim3(128, 4, 3), 256, 0, stream>>>(
            qbb, outb, Wt + (size_t)l * 262144,
            bq + l * E_, bk + l * E_, bv + l * E_, Qb, nullptr, nullptr,
            nullptr, nullptr);
        attn_mfma_kernel<<<B_ * H_ * (S_ / 64), 256, 0, stream>>>(
            Qb, Qb + HS, Qb + 2 * HS, pkb, pos_value, mgb);
        if (l == L_ - 1) {
            mfma_gemm_kernel<1, 1><<<dim3(128, 4, 1), 256, 0, stream>>>(
                mgb, nullptr, Wt + (size_t)l * 262144 + 3 * 65536,
                bo + l * E_, nullptr, nullptr, nullptr, outf, outb, out_w, y);
        } else {
            mfma_gemm_kernel<1, 0><<<dim3(128, 4, 1), 256, 0, stream>>>(
                mgb, nullptr, Wt + (size_t)l * 262144 + 3 * 65536,
                bo + l * E_, nullptr, nullptr, nullptr, outf, outb, nullptr, nullptr);
        }
    }
}